// Round 1
// 254.247 us; speedup vs baseline: 1.0095x; 1.0095x over previous
//
#include <hip/hip_runtime.h>

// DeepPoly ReLU relaxation, elementwise over N neurons.
//   clamped_alpha = clip(alpha, 0, 1)
//   slope   = max(ub/(ub-lb), 0)
//   out_lb  = (ub < 0) ? 0 : lb*clamped_alpha
//   out_ub  = (lb > 0) ? ub : ub*slope + (-(slope*lb))
// Memory-bound streaming op: 12 B read + 8 B written per neuron (335.5 MB total).
// R2->R3 theory: fills hit 6.65 TB/s store-only; our one-shot blocks drain all
// outstanding reads before dying -> read-depth dips between block launches.
// Fix: persistent grid-stride waves + 2-deep software pipeline so each wave
// keeps 12 nontemporal 16B loads in flight continuously.

typedef float vfloat4 __attribute__((ext_vector_type(4)));

__device__ __forceinline__ void relax_one(float lb, float ub, float al,
                                          float& olb, float& oub) {
    float ca    = fminf(fmaxf(al, 0.0f), 1.0f);
    float slope = fmaxf(ub / (ub - lb), 0.0f);
    // Mirror reference arithmetic order exactly (no algebraic refactor):
    float uc_bias = -(slope * lb);
    float uc_diag = (lb > 0.0f) ? 1.0f : slope;
    float lc_diag = (ub < 0.0f) ? 0.0f : ca;
    float ub_bias = (lb > 0.0f) ? 0.0f : uc_bias;
    olb = lb * lc_diag;
    oub = ub * uc_diag + ub_bias;
}

__device__ __forceinline__ void relax_vec4(const vfloat4& lb, const vfloat4& ub,
                                           const vfloat4& al,
                                           vfloat4& olb, vfloat4& oub) {
#pragma unroll
    for (int c = 0; c < 4; ++c) {
        float olbc, oubc;
        relax_one(lb[c], ub[c], al[c], olbc, oubc);
        olb[c] = olbc;
        oub[c] = oubc;
    }
}

constexpr int THREADS = 256;
constexpr int K = 4;               // float4 chunks per thread per tile
constexpr int TILE = THREADS * K;  // float4s per block per tile
constexpr int MAX_BLOCKS = 2048;   // 8 blocks/CU on 256 CUs; grid-stride the rest

struct Tile {
    vfloat4 lb[K], ub[K], al[K];
};

__device__ __forceinline__ void load_tile(Tile& t,
                                          const vfloat4* __restrict__ lb4,
                                          const vfloat4* __restrict__ ub4,
                                          const vfloat4* __restrict__ al4,
                                          int base) {
#pragma unroll
    for (int j = 0; j < K; ++j) {
        int i = base + j * THREADS;
        t.lb[j] = __builtin_nontemporal_load(&lb4[i]);
        t.ub[j] = __builtin_nontemporal_load(&ub4[i]);
        t.al[j] = __builtin_nontemporal_load(&al4[i]);
    }
}

__device__ __forceinline__ void process_tile(const Tile& t,
                                             vfloat4* __restrict__ out_lb4,
                                             vfloat4* __restrict__ out_ub4,
                                             int base) {
#pragma unroll
    for (int j = 0; j < K; ++j) {
        int i = base + j * THREADS;
        vfloat4 olb, oub;
        relax_vec4(t.lb[j], t.ub[j], t.al[j], olb, oub);
        __builtin_nontemporal_store(olb, &out_lb4[i]);
        __builtin_nontemporal_store(oub, &out_ub4[i]);
    }
}

__global__ __launch_bounds__(THREADS) void verify_relu_gs(
    const vfloat4* __restrict__ lb4,
    const vfloat4* __restrict__ ub4,
    const vfloat4* __restrict__ al4,
    vfloat4* __restrict__ out_lb4,
    vfloat4* __restrict__ out_ub4,
    int n4)
{
    const int stride = (int)gridDim.x * TILE;
    int base = blockIdx.x * TILE + threadIdx.x;

    // 2-deep software pipeline: while tile A is being processed/stored,
    // tile B's 12 loads are already in flight.
    Tile A;
    bool validA = (base + (K - 1) * THREADS < n4);
    if (validA) load_tile(A, lb4, ub4, al4, base);

    while (validA) {
        int nbase = base + stride;
        bool validB = (nbase + (K - 1) * THREADS < n4);
        Tile B;
        if (validB) load_tile(B, lb4, ub4, al4, nbase);  // issue next-tile loads first
        process_tile(A, out_lb4, out_ub4, base);         // compute+store current
        if (validB) A = B;  // register rotation (SSA-renamed, cheap vs. memory)
        base = nbase;
        validA = validB;
    }

    // Tail: the one partial tile per thread-stream (if any). Since
    // stride >= TILE > (K-1)*THREADS, at most one partial tile exists per
    // thread and everything past it is fully out of bounds.
#pragma unroll
    for (int j = 0; j < K; ++j) {
        int i = base + j * THREADS;
        if (i < n4) {
            vfloat4 lb = __builtin_nontemporal_load(&lb4[i]);
            vfloat4 ub = __builtin_nontemporal_load(&ub4[i]);
            vfloat4 al = __builtin_nontemporal_load(&al4[i]);
            vfloat4 olb, oub;
            relax_vec4(lb, ub, al, olb, oub);
            __builtin_nontemporal_store(olb, &out_lb4[i]);
            __builtin_nontemporal_store(oub, &out_ub4[i]);
        }
    }
}

// Scalar tail (only used if n % 4 != 0; N=16777216 is divisible by 4).
__global__ __launch_bounds__(64) void verify_relu_tail(
    const float* __restrict__ lb,
    const float* __restrict__ ub,
    const float* __restrict__ al,
    float* __restrict__ out_lb,
    float* __restrict__ out_ub,
    int start, int n)
{
    int i = start + blockIdx.x * blockDim.x + threadIdx.x;
    if (i >= n) return;
    float olb, oub;
    relax_one(lb[i], ub[i], al[i], olb, oub);
    out_lb[i] = olb;
    out_ub[i] = oub;
}

extern "C" void kernel_launch(void* const* d_in, const int* in_sizes, int n_in,
                              void* d_out, int out_size, void* d_ws, size_t ws_size,
                              hipStream_t stream) {
    const float* lb = (const float*)d_in[0];
    const float* ub = (const float*)d_in[1];
    const float* al = (const float*)d_in[2];
    float* out_lb = (float*)d_out;
    int n = in_sizes[0];
    float* out_ub = out_lb + n;

    int n4 = n / 4;
    if (n4 > 0) {
        int blocks = (n4 + TILE - 1) / TILE;
        if (blocks > MAX_BLOCKS) blocks = MAX_BLOCKS;
        verify_relu_gs<<<blocks, THREADS, 0, stream>>>(
            (const vfloat4*)lb, (const vfloat4*)ub, (const vfloat4*)al,
            (vfloat4*)out_lb, (vfloat4*)out_ub, n4);
    }
    int tail_start = n4 * 4;
    if (tail_start < n) {
        int tail_n = n - tail_start;
        int blocks = (tail_n + 63) / 64;
        verify_relu_tail<<<blocks, 64, 0, stream>>>(
            lb, ub, al, out_lb, out_ub, tail_start, n);
    }
}